// Round 1
// baseline (451.080 us; speedup 1.0000x reference)
//
#include <hip/hip_runtime.h>
#include <math.h>

#define NN 50000
#define NE 500000
#define HH 4
#define CC 64
#define HC 256
#define PD 16
#define XD 272
#define NEG 0.2f
#define SB 1024

// ---------------- zero scratch ----------------
__global__ void k_zero(int* counts, int* cursor, float* gram) {
    int i = blockIdx.x * blockDim.x + threadIdx.x;
    if (i < NN) { counts[i] = 0; cursor[i] = 0; }
    if (i < 16) gram[i] = 0.f;
}

// ---------------- GEMM: content = Xc @ W^T, fused score epilogue ----------------
// block = 256 threads, tile = 64 nodes x 64 cols (one head), K=256 in chunks of 16.
__global__ __launch_bounds__(256) void k_gemm(const float* __restrict__ x,
                                              const float* __restrict__ w,
                                              const float* __restrict__ att,
                                              const float* __restrict__ patt,
                                              float* __restrict__ content,
                                              float* __restrict__ ssrc,
                                              float* __restrict__ sdst) {
    __shared__ float As[16][68];  // [k][node], padded
    __shared__ float Bs[16][68];  // [k][col]
    const int h = blockIdx.y;
    const int nb = blockIdx.x * 64;
    const int tid = threadIdx.x;
    const int tx = tid & 15, ty = tid >> 4;
    const int lr = tid >> 2;   // 0..63 row within tile
    const int lq = tid & 3;    // 0..3 k-quad

    float acc[4][4];
#pragma unroll
    for (int i = 0; i < 4; i++)
#pragma unroll
        for (int j = 0; j < 4; j++) acc[i][j] = 0.f;

    for (int kt = 0; kt < 16; kt++) {
        float4 av = make_float4(0.f, 0.f, 0.f, 0.f);
        int n = nb + lr;
        if (n < NN) av = *(const float4*)&x[(size_t)n * XD + kt * 16 + lq * 4];
        float4 bv = *(const float4*)&w[(size_t)(h * 64 + lr) * 256 + kt * 16 + lq * 4];
        __syncthreads();
        As[lq * 4 + 0][lr] = av.x; As[lq * 4 + 1][lr] = av.y;
        As[lq * 4 + 2][lr] = av.z; As[lq * 4 + 3][lr] = av.w;
        Bs[lq * 4 + 0][lr] = bv.x; Bs[lq * 4 + 1][lr] = bv.y;
        Bs[lq * 4 + 2][lr] = bv.z; Bs[lq * 4 + 3][lr] = bv.w;
        __syncthreads();
#pragma unroll
        for (int kk = 0; kk < 16; kk++) {
            float4 a4 = *(const float4*)&As[kk][ty * 4];
            float4 b4 = *(const float4*)&Bs[kk][tx * 4];
            float a[4] = {a4.x, a4.y, a4.z, a4.w};
            float b[4] = {b4.x, b4.y, b4.z, b4.w};
#pragma unroll
            for (int i = 0; i < 4; i++)
#pragma unroll
                for (int j = 0; j < 4; j++) acc[i][j] += a[i] * b[j];
        }
    }

    // fused attention-score partials: this block owns head h for its 64 nodes
    float paA[4], paB[4];
#pragma unroll
    for (int i = 0; i < 4; i++) {
        float sa = 0.f, sb = 0.f;
#pragma unroll
        for (int j = 0; j < 4; j++) {
            int c = tx * 4 + j;
            sa += acc[i][j] * att[h * 128 + c];
            sb += acc[i][j] * att[h * 128 + 64 + c];
        }
        paA[i] = sa; paB[i] = sb;
    }
#pragma unroll
    for (int m = 1; m < 16; m <<= 1) {
#pragma unroll
        for (int i = 0; i < 4; i++) {
            paA[i] += __shfl_xor(paA[i], m, 64);
            paB[i] += __shfl_xor(paB[i], m, 64);
        }
    }

#pragma unroll
    for (int i = 0; i < 4; i++) {
        int n = nb + ty * 4 + i;
        if (n < NN) {
            *(float4*)&content[(size_t)n * 256 + h * 64 + tx * 4] =
                make_float4(acc[i][0], acc[i][1], acc[i][2], acc[i][3]);
            if (tx == 0) {
                float pa = paA[i], pb = paB[i];
#pragma unroll
                for (int d = 0; d < 16; d++) {
                    float pv = x[(size_t)n * XD + 256 + d];
                    pa += pv * patt[h * 32 + d];
                    pb += pv * patt[h * 32 + 16 + d];
                }
                ssrc[n * 4 + h] = pa;
                sdst[n * 4 + h] = pb;
            }
        }
    }
}

// ---------------- edge bucketing by row ----------------
__global__ void k_count(const int* __restrict__ row, int* __restrict__ counts) {
    int e = blockIdx.x * blockDim.x + threadIdx.x;
    if (e < NE) atomicAdd(&counts[row[e]], 1);
}

__global__ __launch_bounds__(SB) void k_scan1(const int* __restrict__ counts, int* tmp, int* bsum) {
    __shared__ int s[SB];
    int i = blockIdx.x * SB + threadIdx.x;
    int v = (i < NN) ? counts[i] : 0;
    s[threadIdx.x] = v;
    __syncthreads();
    for (int off = 1; off < SB; off <<= 1) {
        int t = (threadIdx.x >= off) ? s[threadIdx.x - off] : 0;
        __syncthreads();
        s[threadIdx.x] += t;
        __syncthreads();
    }
    if (i < NN) tmp[i] = s[threadIdx.x];
    if (threadIdx.x == SB - 1) bsum[blockIdx.x] = s[SB - 1];
}

__global__ void k_scan2(const int* bsum, int* bcar, int nb) {
    if (threadIdx.x == 0 && blockIdx.x == 0) {
        int c = 0;
        for (int b = 0; b < nb; b++) { bcar[b] = c; c += bsum[b]; }
    }
}

__global__ void k_scan3(const int* tmp, const int* counts, const int* bcar, int* off) {
    int i = blockIdx.x * blockDim.x + threadIdx.x;
    if (i < NN) off[i] = tmp[i] - counts[i] + bcar[i / SB];
}

__global__ void k_scatter(const int* __restrict__ row, const int* __restrict__ col,
                          const int* __restrict__ off, int* __restrict__ cursor,
                          int* __restrict__ sorted) {
    int e = blockIdx.x * blockDim.x + threadIdx.x;
    if (e < NE) {
        int r = row[e];
        int p = off[r] + atomicAdd(&cursor[r], 1);
        sorted[p] = col[e];
    }
}

// ---------------- per-node softmax + aggregation (1 wave / node) ----------------
__global__ __launch_bounds__(256) void k_node(const float* __restrict__ content,
                                              const float* __restrict__ ssrc,
                                              const float* __restrict__ sdst,
                                              const int* __restrict__ counts,
                                              const int* __restrict__ off,
                                              const int* __restrict__ sorted,
                                              const float* __restrict__ bias,
                                              float* __restrict__ out,
                                              float* __restrict__ gram) {
    __shared__ float gsh[16];
    const int lane = threadIdx.x & 63;
    const int n = blockIdx.x * 4 + (threadIdx.x >> 6);   // NN % 4 == 0, no guard
    if (threadIdx.x < 16) gsh[threadIdx.x] = 0.f;
    __syncthreads();

    const int cnt = counts[n], base = off[n];
    const int total = cnt + 1;  // + self loop
    const float4 ss = *(const float4*)&ssrc[n * 4];
    const int nch = (total + 63) >> 6;

    // pass A: segment max of leaky_relu scores
    float m0 = -1e30f, m1 = -1e30f, m2 = -1e30f, m3 = -1e30f;
    for (int ch = 0; ch < nch; ch++) {
        int l = ch * 64 + lane;
        if (l < total) {
            int c = (l < cnt) ? sorted[base + l] : n;
            float4 sd = *(const float4*)&sdst[c * 4];
            float r0 = ss.x + sd.x; r0 = r0 > 0.f ? r0 : NEG * r0;
            float r1 = ss.y + sd.y; r1 = r1 > 0.f ? r1 : NEG * r1;
            float r2 = ss.z + sd.z; r2 = r2 > 0.f ? r2 : NEG * r2;
            float r3 = ss.w + sd.w; r3 = r3 > 0.f ? r3 : NEG * r3;
            m0 = fmaxf(m0, r0); m1 = fmaxf(m1, r1);
            m2 = fmaxf(m2, r2); m3 = fmaxf(m3, r3);
        }
    }
#pragma unroll
    for (int s = 1; s < 64; s <<= 1) {
        m0 = fmaxf(m0, __shfl_xor(m0, s));
        m1 = fmaxf(m1, __shfl_xor(m1, s));
        m2 = fmaxf(m2, __shfl_xor(m2, s));
        m3 = fmaxf(m3, __shfl_xor(m3, s));
    }

    // pass B: segment sum of exp(score - max)
    float s0 = 0.f, s1 = 0.f, s2 = 0.f, s3 = 0.f;
    for (int ch = 0; ch < nch; ch++) {
        int l = ch * 64 + lane;
        if (l < total) {
            int c = (l < cnt) ? sorted[base + l] : n;
            float4 sd = *(const float4*)&sdst[c * 4];
            float r0 = ss.x + sd.x; r0 = r0 > 0.f ? r0 : NEG * r0;
            float r1 = ss.y + sd.y; r1 = r1 > 0.f ? r1 : NEG * r1;
            float r2 = ss.z + sd.z; r2 = r2 > 0.f ? r2 : NEG * r2;
            float r3 = ss.w + sd.w; r3 = r3 > 0.f ? r3 : NEG * r3;
            s0 += expf(r0 - m0); s1 += expf(r1 - m1);
            s2 += expf(r2 - m2); s3 += expf(r3 - m3);
        }
    }
#pragma unroll
    for (int s = 1; s < 64; s <<= 1) {
        s0 += __shfl_xor(s0, s); s1 += __shfl_xor(s1, s);
        s2 += __shfl_xor(s2, s); s3 += __shfl_xor(s3, s);
    }
    const float i0 = 1.f / (s0 + 1e-16f), i1 = 1.f / (s1 + 1e-16f);
    const float i2 = 1.f / (s2 + 1e-16f), i3 = 1.f / (s3 + 1e-16f);

    // pass C: normalized alphas -> gram + weighted aggregation of content[col]
    float4 acc = make_float4(0.f, 0.f, 0.f, 0.f);
    float g[10];
#pragma unroll
    for (int k = 0; k < 10; k++) g[k] = 0.f;
    const float4* c4 = (const float4*)content;
    const int hsel = lane >> 4;

    for (int ch = 0; ch < nch; ch++) {
        int l = ch * 64 + lane;
        int c = n;
        float a0 = 0.f, a1 = 0.f, a2 = 0.f, a3 = 0.f;
        if (l < total) {
            c = (l < cnt) ? sorted[base + l] : n;
            float4 sd = *(const float4*)&sdst[c * 4];
            float r0 = ss.x + sd.x; r0 = r0 > 0.f ? r0 : NEG * r0;
            float r1 = ss.y + sd.y; r1 = r1 > 0.f ? r1 : NEG * r1;
            float r2 = ss.z + sd.z; r2 = r2 > 0.f ? r2 : NEG * r2;
            float r3 = ss.w + sd.w; r3 = r3 > 0.f ? r3 : NEG * r3;
            a0 = expf(r0 - m0) * i0; a1 = expf(r1 - m1) * i1;
            a2 = expf(r2 - m2) * i2; a3 = expf(r3 - m3) * i3;
        }
        g[0] += a0 * a0; g[1] += a0 * a1; g[2] += a0 * a2; g[3] += a0 * a3;
        g[4] += a1 * a1; g[5] += a1 * a2; g[6] += a1 * a3;
        g[7] += a2 * a2; g[8] += a2 * a3; g[9] += a3 * a3;

        int cc = min(64, total - ch * 64);
        for (int e = 0; e < cc; e++) {
            float b0 = __shfl(a0, e), b1 = __shfl(a1, e);
            float b2 = __shfl(a2, e), b3 = __shfl(a3, e);
            int ce = __shfl(c, e);
            float mya = hsel == 0 ? b0 : hsel == 1 ? b1 : hsel == 2 ? b2 : b3;
            float4 cv = c4[(size_t)ce * 64 + lane];
            acc.x += mya * cv.x; acc.y += mya * cv.y;
            acc.z += mya * cv.z; acc.w += mya * cv.w;
        }
    }

    float4 bv = ((const float4*)bias)[lane];
    acc.x += bv.x; acc.y += bv.y; acc.z += bv.z; acc.w += bv.w;
    ((float4*)out)[(size_t)n * 64 + lane] = acc;

    // gram: wave reduce -> LDS -> global
#pragma unroll
    for (int s = 1; s < 64; s <<= 1) {
#pragma unroll
        for (int k = 0; k < 10; k++) g[k] += __shfl_xor(g[k], s);
    }
    if (lane == 0) {
#pragma unroll
        for (int k = 0; k < 10; k++) atomicAdd(&gsh[k], g[k]);
    }
    __syncthreads();
    if (threadIdx.x < 10) atomicAdd(&gram[threadIdx.x], gsh[threadIdx.x]);
}

// ---------------- diversity loss ----------------
__global__ void k_final(const float* __restrict__ gram, float* __restrict__ out_div) {
    if (threadIdx.x == 0 && blockIdx.x == 0) {
        float g00 = gram[0], g01 = gram[1], g02 = gram[2], g03 = gram[3];
        float g11 = gram[4], g12 = gram[5], g13 = gram[6];
        float g22 = gram[7], g23 = gram[8], g33 = gram[9];
        float n0 = fmaxf(sqrtf(g00), 1e-8f), n1 = fmaxf(sqrtf(g11), 1e-8f);
        float n2 = fmaxf(sqrtf(g22), 1e-8f), n3 = fmaxf(sqrtf(g33), 1e-8f);
        float s = g01 / (n0 * n1) + g02 / (n0 * n2) + g03 / (n0 * n3) +
                  g12 / (n1 * n2) + g13 / (n1 * n3) + g23 / (n2 * n3);
        s *= 2.0f;                       // symmetric off-diagonal
        out_div[0] = s / 16.0f * 0.1f;   // mean over 4x4 then * DIVERSITY_WEIGHT
    }
}

extern "C" void kernel_launch(void* const* d_in, const int* in_sizes, int n_in,
                              void* d_out, int out_size, void* d_ws, size_t ws_size,
                              hipStream_t stream) {
    const float* x    = (const float*)d_in[0];
    const int*   ei   = (const int*)d_in[1];
    const int*   row  = ei;
    const int*   col  = ei + NE;
    const float* w    = (const float*)d_in[2];
    const float* att  = (const float*)d_in[3];
    const float* patt = (const float*)d_in[4];
    const float* bias = (const float*)d_in[5];
    float* out = (float*)d_out;

    char* p = (char*)d_ws;
    float* content = (float*)p; p += (size_t)NN * 256 * 4;
    float* ssrc    = (float*)p; p += (size_t)NN * 4 * 4;
    float* sdst    = (float*)p; p += (size_t)NN * 4 * 4;
    float* gram    = (float*)p; p += 16 * 4;
    int* counts    = (int*)p;   p += (size_t)NN * 4;
    int* cursor    = (int*)p;   p += (size_t)NN * 4;
    int* offs      = (int*)p;   p += (size_t)NN * 4;
    int* tmp       = (int*)p;   p += (size_t)NN * 4;
    int* bsum      = (int*)p;   p += 64 * 4;
    int* bcar      = (int*)p;   p += 64 * 4;
    int* sorted    = (int*)p;   p += (size_t)NE * 4;

    k_zero<<<(NN + 255) / 256, 256, 0, stream>>>(counts, cursor, gram);

    dim3 gg((NN + 63) / 64, HH);
    k_gemm<<<gg, 256, 0, stream>>>(x, w, att, patt, content, ssrc, sdst);

    k_count<<<(NE + 255) / 256, 256, 0, stream>>>(row, counts);
    int nb1 = (NN + SB - 1) / SB;
    k_scan1<<<nb1, SB, 0, stream>>>(counts, tmp, bsum);
    k_scan2<<<1, 64, 0, stream>>>(bsum, bcar, nb1);
    k_scan3<<<(NN + 255) / 256, 256, 0, stream>>>(tmp, counts, bcar, offs);
    k_scatter<<<(NE + 255) / 256, 256, 0, stream>>>(row, col, offs, cursor, sorted);

    k_node<<<NN / 4, 256, 0, stream>>>(content, ssrc, sdst, counts, offs, sorted,
                                       bias, out, gram);
    k_final<<<1, 64, 0, stream>>>(gram, out + (size_t)NN * 256);
}

// Round 2
// 436.969 us; speedup vs baseline: 1.0323x; 1.0323x over previous
//
#include <hip/hip_runtime.h>
#include <math.h>

#define NN 50000
#define NE 500000
#define HH 4
#define CC 64
#define HC 256
#define PD 16
#define XD 272
#define NEG 0.2f
#define SB 1024

typedef _Float16 half4 __attribute__((ext_vector_type(4)));

// ---------------- zero scratch ----------------
__global__ void k_zero(int* counts, int* cursor, float* gram) {
    int i = blockIdx.x * blockDim.x + threadIdx.x;
    if (i < NN) { counts[i] = 0; cursor[i] = 0; }
    if (i < 16) gram[i] = 0.f;
}

// ---------------- GEMM: content = Xc @ W^T (fp32 compute, fp16 store) ----------------
// block = 256 threads, tile = 64 nodes x 64 cols (one head), K=256 in chunks of 16.
__global__ __launch_bounds__(256) void k_gemm(const float* __restrict__ x,
                                              const float* __restrict__ w,
                                              const float* __restrict__ att,
                                              const float* __restrict__ patt,
                                              _Float16* __restrict__ content,
                                              float* __restrict__ ssrc,
                                              float* __restrict__ sdst) {
    __shared__ float As[16][68];  // [k][node], padded
    __shared__ float Bs[16][68];  // [k][col]
    const int h = blockIdx.y;
    const int nb = blockIdx.x * 64;
    const int tid = threadIdx.x;
    const int tx = tid & 15, ty = tid >> 4;
    const int lr = tid >> 2;   // 0..63 row within tile
    const int lq = tid & 3;    // 0..3 k-quad

    float acc[4][4];
#pragma unroll
    for (int i = 0; i < 4; i++)
#pragma unroll
        for (int j = 0; j < 4; j++) acc[i][j] = 0.f;

    for (int kt = 0; kt < 16; kt++) {
        float4 av = make_float4(0.f, 0.f, 0.f, 0.f);
        int n = nb + lr;
        if (n < NN) av = *(const float4*)&x[(size_t)n * XD + kt * 16 + lq * 4];
        float4 bv = *(const float4*)&w[(size_t)(h * 64 + lr) * 256 + kt * 16 + lq * 4];
        __syncthreads();
        As[lq * 4 + 0][lr] = av.x; As[lq * 4 + 1][lr] = av.y;
        As[lq * 4 + 2][lr] = av.z; As[lq * 4 + 3][lr] = av.w;
        Bs[lq * 4 + 0][lr] = bv.x; Bs[lq * 4 + 1][lr] = bv.y;
        Bs[lq * 4 + 2][lr] = bv.z; Bs[lq * 4 + 3][lr] = bv.w;
        __syncthreads();
#pragma unroll
        for (int kk = 0; kk < 16; kk++) {
            float4 a4 = *(const float4*)&As[kk][ty * 4];
            float4 b4 = *(const float4*)&Bs[kk][tx * 4];
            float a[4] = {a4.x, a4.y, a4.z, a4.w};
            float b[4] = {b4.x, b4.y, b4.z, b4.w};
#pragma unroll
            for (int i = 0; i < 4; i++)
#pragma unroll
                for (int j = 0; j < 4; j++) acc[i][j] += a[i] * b[j];
        }
    }

    // fused attention-score partials: this block owns head h for its 64 nodes
    float paA[4], paB[4];
#pragma unroll
    for (int i = 0; i < 4; i++) {
        float sa = 0.f, sb = 0.f;
#pragma unroll
        for (int j = 0; j < 4; j++) {
            int c = tx * 4 + j;
            sa += acc[i][j] * att[h * 128 + c];
            sb += acc[i][j] * att[h * 128 + 64 + c];
        }
        paA[i] = sa; paB[i] = sb;
    }
#pragma unroll
    for (int m = 1; m < 16; m <<= 1) {
#pragma unroll
        for (int i = 0; i < 4; i++) {
            paA[i] += __shfl_xor(paA[i], m, 64);
            paB[i] += __shfl_xor(paB[i], m, 64);
        }
    }

#pragma unroll
    for (int i = 0; i < 4; i++) {
        int n = nb + ty * 4 + i;
        if (n < NN) {
            half4 hv;
            hv.x = (_Float16)acc[i][0]; hv.y = (_Float16)acc[i][1];
            hv.z = (_Float16)acc[i][2]; hv.w = (_Float16)acc[i][3];
            *(half4*)&content[(size_t)n * 256 + h * 64 + tx * 4] = hv;
            if (tx == 0) {
                float pa = paA[i], pb = paB[i];
#pragma unroll
                for (int d = 0; d < 16; d++) {
                    float pv = x[(size_t)n * XD + 256 + d];
                    pa += pv * patt[h * 32 + d];
                    pb += pv * patt[h * 32 + 16 + d];
                }
                ssrc[n * 4 + h] = pa;
                sdst[n * 4 + h] = pb;
            }
        }
    }
}

// ---------------- edge bucketing by row ----------------
__global__ void k_count(const int* __restrict__ row, int* __restrict__ counts) {
    int e = blockIdx.x * blockDim.x + threadIdx.x;
    if (e < NE) atomicAdd(&counts[row[e]], 1);
}

__global__ __launch_bounds__(SB) void k_scan1(const int* __restrict__ counts, int* tmp, int* bsum) {
    __shared__ int s[SB];
    int i = blockIdx.x * SB + threadIdx.x;
    int v = (i < NN) ? counts[i] : 0;
    s[threadIdx.x] = v;
    __syncthreads();
    for (int off = 1; off < SB; off <<= 1) {
        int t = (threadIdx.x >= off) ? s[threadIdx.x - off] : 0;
        __syncthreads();
        s[threadIdx.x] += t;
        __syncthreads();
    }
    if (i < NN) tmp[i] = s[threadIdx.x];
    if (threadIdx.x == SB - 1) bsum[blockIdx.x] = s[SB - 1];
}

__global__ void k_scan2(const int* bsum, int* bcar, int nb) {
    if (threadIdx.x == 0 && blockIdx.x == 0) {
        int c = 0;
        for (int b = 0; b < nb; b++) { bcar[b] = c; c += bsum[b]; }
    }
}

__global__ void k_scan3(const int* tmp, const int* counts, const int* bcar, int* off) {
    int i = blockIdx.x * blockDim.x + threadIdx.x;
    if (i < NN) off[i] = tmp[i] - counts[i] + bcar[i / SB];
}

__global__ void k_scatter(const int* __restrict__ row, const int* __restrict__ col,
                          const int* __restrict__ off, int* __restrict__ cursor,
                          int* __restrict__ sorted) {
    int e = blockIdx.x * blockDim.x + threadIdx.x;
    if (e < NE) {
        int r = row[e];
        int p = off[r] + atomicAdd(&cursor[r], 1);
        sorted[p] = col[e];
    }
}

// ---------------- per-node softmax + aggregation (1 wave / node) ----------------
__global__ __launch_bounds__(256) void k_node(const _Float16* __restrict__ content,
                                              const float* __restrict__ ssrc,
                                              const float* __restrict__ sdst,
                                              const int* __restrict__ counts,
                                              const int* __restrict__ off,
                                              const int* __restrict__ sorted,
                                              const float* __restrict__ bias,
                                              float* __restrict__ out,
                                              float* __restrict__ gram) {
    __shared__ float gsh[16];
    __shared__ float ash[4][64][4];   // per-wave alpha cache [wave][edge][head]
    __shared__ int   csh[4][64];      // per-wave col cache
    const int w = threadIdx.x >> 6;
    const int lane = threadIdx.x & 63;
    const int n = blockIdx.x * 4 + w;   // NN % 4 == 0, no guard
    if (threadIdx.x < 16) gsh[threadIdx.x] = 0.f;
    __syncthreads();

    const int cnt = counts[n], base = off[n];
    const int total = cnt + 1;  // + self loop
    const float4 ss = *(const float4*)&ssrc[n * 4];
    const int hsel = lane >> 4;
    const half4* c4 = (const half4*)content;

    float4 acc = make_float4(0.f, 0.f, 0.f, 0.f);
    float g[10];
#pragma unroll
    for (int k = 0; k < 10; k++) g[k] = 0.f;

    if (total <= 64) {
        // ---- fast path: one edge per lane, scores computed once ----
        const int l = lane;
        const bool act = (l < total);
        const int c = (l < cnt) ? sorted[base + l] : n;
        float4 sd = *(const float4*)&sdst[c * 4];
        float r0 = ss.x + sd.x; r0 = r0 > 0.f ? r0 : NEG * r0;
        float r1 = ss.y + sd.y; r1 = r1 > 0.f ? r1 : NEG * r1;
        float r2 = ss.z + sd.z; r2 = r2 > 0.f ? r2 : NEG * r2;
        float r3 = ss.w + sd.w; r3 = r3 > 0.f ? r3 : NEG * r3;
        float m0 = act ? r0 : -1e30f, m1 = act ? r1 : -1e30f;
        float m2 = act ? r2 : -1e30f, m3 = act ? r3 : -1e30f;
#pragma unroll
        for (int s = 1; s < 64; s <<= 1) {
            m0 = fmaxf(m0, __shfl_xor(m0, s));
            m1 = fmaxf(m1, __shfl_xor(m1, s));
            m2 = fmaxf(m2, __shfl_xor(m2, s));
            m3 = fmaxf(m3, __shfl_xor(m3, s));
        }
        float e0 = act ? __expf(r0 - m0) : 0.f;
        float e1 = act ? __expf(r1 - m1) : 0.f;
        float e2 = act ? __expf(r2 - m2) : 0.f;
        float e3 = act ? __expf(r3 - m3) : 0.f;
        float s0 = e0, s1 = e1, s2 = e2, s3 = e3;
#pragma unroll
        for (int s = 1; s < 64; s <<= 1) {
            s0 += __shfl_xor(s0, s); s1 += __shfl_xor(s1, s);
            s2 += __shfl_xor(s2, s); s3 += __shfl_xor(s3, s);
        }
        float a0 = e0 / (s0 + 1e-16f), a1 = e1 / (s1 + 1e-16f);
        float a2 = e2 / (s2 + 1e-16f), a3 = e3 / (s3 + 1e-16f);

        g[0] = a0 * a0; g[1] = a0 * a1; g[2] = a0 * a2; g[3] = a0 * a3;
        g[4] = a1 * a1; g[5] = a1 * a2; g[6] = a1 * a3;
        g[7] = a2 * a2; g[8] = a2 * a3; g[9] = a3 * a3;

        ash[w][l][0] = a0; ash[w][l][1] = a1;
        ash[w][l][2] = a2; ash[w][l][3] = a3;
        csh[w][l] = c;
        // same-wave LDS write->read: compiler inserts lgkmcnt, no barrier needed

        // ---- aggregation: 4x unrolled, 4 gathers in flight ----
        int e = 0;
        for (; e + 4 <= total; e += 4) {
            int c0 = csh[w][e + 0], c1 = csh[w][e + 1];
            int c2 = csh[w][e + 2], c3 = csh[w][e + 3];
            float b0 = ash[w][e + 0][hsel], b1 = ash[w][e + 1][hsel];
            float b2 = ash[w][e + 2][hsel], b3 = ash[w][e + 3][hsel];
            half4 v0 = c4[(size_t)c0 * 64 + lane];
            half4 v1 = c4[(size_t)c1 * 64 + lane];
            half4 v2 = c4[(size_t)c2 * 64 + lane];
            half4 v3 = c4[(size_t)c3 * 64 + lane];
            acc.x += b0 * (float)v0.x + b1 * (float)v1.x + b2 * (float)v2.x + b3 * (float)v3.x;
            acc.y += b0 * (float)v0.y + b1 * (float)v1.y + b2 * (float)v2.y + b3 * (float)v3.y;
            acc.z += b0 * (float)v0.z + b1 * (float)v1.z + b2 * (float)v2.z + b3 * (float)v3.z;
            acc.w += b0 * (float)v0.w + b1 * (float)v1.w + b2 * (float)v2.w + b3 * (float)v3.w;
        }
        for (; e < total; e++) {
            int ce = csh[w][e];
            float b = ash[w][e][hsel];
            half4 v = c4[(size_t)ce * 64 + lane];
            acc.x += b * (float)v.x; acc.y += b * (float)v.y;
            acc.z += b * (float)v.z; acc.w += b * (float)v.w;
        }
    } else {
        // ---- generic chunked path (degree >= 64; rare) ----
        const int nch = (total + 63) >> 6;
        float m0 = -1e30f, m1 = -1e30f, m2 = -1e30f, m3 = -1e30f;
        for (int ch = 0; ch < nch; ch++) {
            int l = ch * 64 + lane;
            if (l < total) {
                int c = (l < cnt) ? sorted[base + l] : n;
                float4 sd = *(const float4*)&sdst[c * 4];
                float r0 = ss.x + sd.x; r0 = r0 > 0.f ? r0 : NEG * r0;
                float r1 = ss.y + sd.y; r1 = r1 > 0.f ? r1 : NEG * r1;
                float r2 = ss.z + sd.z; r2 = r2 > 0.f ? r2 : NEG * r2;
                float r3 = ss.w + sd.w; r3 = r3 > 0.f ? r3 : NEG * r3;
                m0 = fmaxf(m0, r0); m1 = fmaxf(m1, r1);
                m2 = fmaxf(m2, r2); m3 = fmaxf(m3, r3);
            }
        }
#pragma unroll
        for (int s = 1; s < 64; s <<= 1) {
            m0 = fmaxf(m0, __shfl_xor(m0, s));
            m1 = fmaxf(m1, __shfl_xor(m1, s));
            m2 = fmaxf(m2, __shfl_xor(m2, s));
            m3 = fmaxf(m3, __shfl_xor(m3, s));
        }
        float s0 = 0.f, s1 = 0.f, s2 = 0.f, s3 = 0.f;
        for (int ch = 0; ch < nch; ch++) {
            int l = ch * 64 + lane;
            if (l < total) {
                int c = (l < cnt) ? sorted[base + l] : n;
                float4 sd = *(const float4*)&sdst[c * 4];
                float r0 = ss.x + sd.x; r0 = r0 > 0.f ? r0 : NEG * r0;
                float r1 = ss.y + sd.y; r1 = r1 > 0.f ? r1 : NEG * r1;
                float r2 = ss.z + sd.z; r2 = r2 > 0.f ? r2 : NEG * r2;
                float r3 = ss.w + sd.w; r3 = r3 > 0.f ? r3 : NEG * r3;
                s0 += __expf(r0 - m0); s1 += __expf(r1 - m1);
                s2 += __expf(r2 - m2); s3 += __expf(r3 - m3);
            }
        }
#pragma unroll
        for (int s = 1; s < 64; s <<= 1) {
            s0 += __shfl_xor(s0, s); s1 += __shfl_xor(s1, s);
            s2 += __shfl_xor(s2, s); s3 += __shfl_xor(s3, s);
        }
        const float i0 = 1.f / (s0 + 1e-16f), i1 = 1.f / (s1 + 1e-16f);
        const float i2 = 1.f / (s2 + 1e-16f), i3 = 1.f / (s3 + 1e-16f);

        for (int ch = 0; ch < nch; ch++) {
            int l = ch * 64 + lane;
            int c = n;
            float a0 = 0.f, a1 = 0.f, a2 = 0.f, a3 = 0.f;
            if (l < total) {
                c = (l < cnt) ? sorted[base + l] : n;
                float4 sd = *(const float4*)&sdst[c * 4];
                float r0 = ss.x + sd.x; r0 = r0 > 0.f ? r0 : NEG * r0;
                float r1 = ss.y + sd.y; r1 = r1 > 0.f ? r1 : NEG * r1;
                float r2 = ss.z + sd.z; r2 = r2 > 0.f ? r2 : NEG * r2;
                float r3 = ss.w + sd.w; r3 = r3 > 0.f ? r3 : NEG * r3;
                a0 = __expf(r0 - m0) * i0; a1 = __expf(r1 - m1) * i1;
                a2 = __expf(r2 - m2) * i2; a3 = __expf(r3 - m3) * i3;
            }
            g[0] += a0 * a0; g[1] += a0 * a1; g[2] += a0 * a2; g[3] += a0 * a3;
            g[4] += a1 * a1; g[5] += a1 * a2; g[6] += a1 * a3;
            g[7] += a2 * a2; g[8] += a2 * a3; g[9] += a3 * a3;

            int cc = min(64, total - ch * 64);
            for (int e = 0; e < cc; e++) {
                float b0 = __shfl(a0, e), b1 = __shfl(a1, e);
                float b2 = __shfl(a2, e), b3 = __shfl(a3, e);
                int ce = __shfl(c, e);
                float mya = hsel == 0 ? b0 : hsel == 1 ? b1 : hsel == 2 ? b2 : b3;
                half4 cv = c4[(size_t)ce * 64 + lane];
                acc.x += mya * (float)cv.x; acc.y += mya * (float)cv.y;
                acc.z += mya * (float)cv.z; acc.w += mya * (float)cv.w;
            }
        }
    }

    float4 bv = ((const float4*)bias)[lane];
    acc.x += bv.x; acc.y += bv.y; acc.z += bv.z; acc.w += bv.w;
    ((float4*)out)[(size_t)n * 64 + lane] = acc;

    // gram: wave reduce -> LDS -> global
#pragma unroll
    for (int s = 1; s < 64; s <<= 1) {
#pragma unroll
        for (int k = 0; k < 10; k++) g[k] += __shfl_xor(g[k], s);
    }
    if (lane == 0) {
#pragma unroll
        for (int k = 0; k < 10; k++) atomicAdd(&gsh[k], g[k]);
    }
    __syncthreads();
    if (threadIdx.x < 10) atomicAdd(&gram[threadIdx.x], gsh[threadIdx.x]);
}

// ---------------- diversity loss ----------------
__global__ void k_final(const float* __restrict__ gram, float* __restrict__ out_div) {
    if (threadIdx.x == 0 && blockIdx.x == 0) {
        float g00 = gram[0], g01 = gram[1], g02 = gram[2], g03 = gram[3];
        float g11 = gram[4], g12 = gram[5], g13 = gram[6];
        float g22 = gram[7], g23 = gram[8], g33 = gram[9];
        float n0 = fmaxf(sqrtf(g00), 1e-8f), n1 = fmaxf(sqrtf(g11), 1e-8f);
        float n2 = fmaxf(sqrtf(g22), 1e-8f), n3 = fmaxf(sqrtf(g33), 1e-8f);
        float s = g01 / (n0 * n1) + g02 / (n0 * n2) + g03 / (n0 * n3) +
                  g12 / (n1 * n2) + g13 / (n1 * n3) + g23 / (n2 * n3);
        s *= 2.0f;                       // symmetric off-diagonal
        out_div[0] = s / 16.0f * 0.1f;   // mean over 4x4 then * DIVERSITY_WEIGHT
    }
}

extern "C" void kernel_launch(void* const* d_in, const int* in_sizes, int n_in,
                              void* d_out, int out_size, void* d_ws, size_t ws_size,
                              hipStream_t stream) {
    const float* x    = (const float*)d_in[0];
    const int*   ei   = (const int*)d_in[1];
    const int*   row  = ei;
    const int*   col  = ei + NE;
    const float* w    = (const float*)d_in[2];
    const float* att  = (const float*)d_in[3];
    const float* patt = (const float*)d_in[4];
    const float* bias = (const float*)d_in[5];
    float* out = (float*)d_out;

    char* p = (char*)d_ws;
    _Float16* content = (_Float16*)p; p += (size_t)NN * 256 * 2;
    float* ssrc    = (float*)p; p += (size_t)NN * 4 * 4;
    float* sdst    = (float*)p; p += (size_t)NN * 4 * 4;
    float* gram    = (float*)p; p += 16 * 4;
    int* counts    = (int*)p;   p += (size_t)NN * 4;
    int* cursor    = (int*)p;   p += (size_t)NN * 4;
    int* offs      = (int*)p;   p += (size_t)NN * 4;
    int* tmp       = (int*)p;   p += (size_t)NN * 4;
    int* bsum      = (int*)p;   p += 64 * 4;
    int* bcar      = (int*)p;   p += 64 * 4;
    int* sorted    = (int*)p;   p += (size_t)NE * 4;

    k_zero<<<(NN + 255) / 256, 256, 0, stream>>>(counts, cursor, gram);

    dim3 gg((NN + 63) / 64, HH);
    k_gemm<<<gg, 256, 0, stream>>>(x, w, att, patt, content, ssrc, sdst);

    k_count<<<(NE + 255) / 256, 256, 0, stream>>>(row, counts);
    int nb1 = (NN + SB - 1) / SB;
    k_scan1<<<nb1, SB, 0, stream>>>(counts, tmp, bsum);
    k_scan2<<<1, 64, 0, stream>>>(bsum, bcar, nb1);
    k_scan3<<<(NN + 255) / 256, 256, 0, stream>>>(tmp, counts, bcar, offs);
    k_scatter<<<(NE + 255) / 256, 256, 0, stream>>>(row, col, offs, cursor, sorted);

    k_node<<<NN / 4, 256, 0, stream>>>(content, ssrc, sdst, counts, offs, sorted,
                                       bias, out, gram);
    k_final<<<1, 64, 0, stream>>>(gram, out + (size_t)NN * 256);
}

// Round 3
// 337.677 us; speedup vs baseline: 1.3358x; 1.2940x over previous
//
#include <hip/hip_runtime.h>
#include <math.h>

#define NN 50000
#define NE 500000
#define HH 4
#define CC 64
#define HC 256
#define PD 16
#define XD 272
#define NEG 0.2f
#define SB 1024
#define NBLK (NN / 4)   // k_node blocks

typedef _Float16 half4 __attribute__((ext_vector_type(4)));
typedef _Float16 half8 __attribute__((ext_vector_type(8)));
typedef float floatx4 __attribute__((ext_vector_type(4)));

#define SA 40   // LDS tile row stride in halves (32 + 8 pad)

// ---------------- zero scratch ----------------
__global__ void k_zero(int* counts, int* cursor) {
    int i = blockIdx.x * blockDim.x + threadIdx.x;
    if (i < NN) { counts[i] = 0; cursor[i] = 0; }
}

// ---------------- MFMA GEMM: content(fp16) = Xc @ W^T ----------------
// block = 256 thr (4 waves). Tile: 64 nodes x 256 cols. K=256 in 8 steps of 32.
// A,B staged to LDS as fp16 in [row][k] layout (k contiguous -> ds_read_b128 frags).
__global__ __launch_bounds__(256) void k_gemm(const float* __restrict__ x,
                                              const float* __restrict__ w,
                                              _Float16* __restrict__ content) {
    __shared__ _Float16 As[64 * SA];    // [m][k]
    __shared__ _Float16 Bs[256 * SA];   // [n][k]
    const int tid = threadIdx.x;
    const int wv = tid >> 6, lane = tid & 63;
    const int nb = blockIdx.x * 64;
    const int m16 = lane & 15, q = lane >> 4;

    floatx4 acc[4][4];
#pragma unroll
    for (int mt = 0; mt < 4; mt++)
#pragma unroll
        for (int nt = 0; nt < 4; nt++) acc[mt][nt] = (floatx4){0.f, 0.f, 0.f, 0.f};

    const int arow = tid >> 2, akq = (tid & 3) * 8;
    const int anode = nb + arow;

    for (int kt = 0; kt < 8; kt++) {
        const int k0 = kt * 32;
        __syncthreads();
        // stage A: 64 rows x 32 k
        {
            float4 f0 = make_float4(0.f, 0.f, 0.f, 0.f), f1 = f0;
            if (anode < NN) {
                f0 = *(const float4*)&x[(size_t)anode * XD + k0 + akq];
                f1 = *(const float4*)&x[(size_t)anode * XD + k0 + akq + 4];
            }
            half8 hv;
            hv[0] = (_Float16)f0.x; hv[1] = (_Float16)f0.y;
            hv[2] = (_Float16)f0.z; hv[3] = (_Float16)f0.w;
            hv[4] = (_Float16)f1.x; hv[5] = (_Float16)f1.y;
            hv[6] = (_Float16)f1.z; hv[7] = (_Float16)f1.w;
            *(half8*)&As[arow * SA + akq] = hv;
        }
        // stage B: 256 rows x 32 k  (Bs[n][k] = w[n][k]); w is L2-hot
        {
            const float* wr = &w[(size_t)tid * 256 + k0];
#pragma unroll
            for (int i = 0; i < 4; i++) {
                float4 f0 = *(const float4*)&wr[i * 8];
                float4 f1 = *(const float4*)&wr[i * 8 + 4];
                half8 hv;
                hv[0] = (_Float16)f0.x; hv[1] = (_Float16)f0.y;
                hv[2] = (_Float16)f0.z; hv[3] = (_Float16)f0.w;
                hv[4] = (_Float16)f1.x; hv[5] = (_Float16)f1.y;
                hv[6] = (_Float16)f1.z; hv[7] = (_Float16)f1.w;
                *(half8*)&Bs[tid * SA + i * 8] = hv;
            }
        }
        __syncthreads();

        half8 af[4], bf[4];
#pragma unroll
        for (int mt = 0; mt < 4; mt++)
            af[mt] = *(half8*)&As[(mt * 16 + m16) * SA + q * 8];
#pragma unroll
        for (int nt = 0; nt < 4; nt++)
            bf[nt] = *(half8*)&Bs[(wv * 64 + nt * 16 + m16) * SA + q * 8];
#pragma unroll
        for (int mt = 0; mt < 4; mt++)
#pragma unroll
            for (int nt = 0; nt < 4; nt++)
                acc[mt][nt] = __builtin_amdgcn_mfma_f32_16x16x32_f16(
                    af[mt], bf[nt], acc[mt][nt], 0, 0, 0);
    }

    // epilogue: D layout col = lane&15, row = (lane>>4)*4 + reg
#pragma unroll
    for (int mt = 0; mt < 4; mt++) {
#pragma unroll
        for (int r = 0; r < 4; r++) {
            int node = nb + mt * 16 + q * 4 + r;
            if (node < NN) {
#pragma unroll
                for (int nt = 0; nt < 4; nt++) {
                    int col = wv * 64 + nt * 16 + m16;
                    content[(size_t)node * 256 + col] = (_Float16)acc[mt][nt][r];
                }
            }
        }
    }
}

// ---------------- attention scores: ssrc/sdst from content + pos ----------------
// 1 wave / node; lane covers cols [lane*4, lane*4+4), head = lane>>4.
__global__ __launch_bounds__(256) void k_score(const _Float16* __restrict__ content,
                                               const float* __restrict__ x,
                                               const float* __restrict__ att,
                                               const float* __restrict__ patt,
                                               float* __restrict__ ssrc,
                                               float* __restrict__ sdst) {
    const int lane = threadIdx.x & 63;
    const int n = blockIdx.x * 4 + (threadIdx.x >> 6);
    const int h = lane >> 4, j = lane & 15;

    half4 v = ((const half4*)content)[(size_t)n * 64 + lane];
    float pv = x[(size_t)n * XD + 256 + j];   // pos[j]

    float sa = pv * patt[h * 32 + j];
    float sb = pv * patt[h * 32 + 16 + j];
#pragma unroll
    for (int t = 0; t < 4; t++) {
        float cv = (float)v[t];
        sa += cv * att[h * 128 + j * 4 + t];
        sb += cv * att[h * 128 + 64 + j * 4 + t];
    }
#pragma unroll
    for (int m = 1; m < 16; m <<= 1) {
        sa += __shfl_xor(sa, m, 64);
        sb += __shfl_xor(sb, m, 64);
    }
    if (j == 0) {
        ssrc[n * 4 + h] = sa;
        sdst[n * 4 + h] = sb;
    }
}

// ---------------- edge bucketing by row ----------------
__global__ void k_count(const int* __restrict__ row, int* __restrict__ counts) {
    int e = blockIdx.x * blockDim.x + threadIdx.x;
    if (e < NE) atomicAdd(&counts[row[e]], 1);
}

__global__ __launch_bounds__(SB) void k_scan1(const int* __restrict__ counts, int* tmp, int* bsum) {
    __shared__ int s[SB];
    int i = blockIdx.x * SB + threadIdx.x;
    int v = (i < NN) ? counts[i] : 0;
    s[threadIdx.x] = v;
    __syncthreads();
    for (int off = 1; off < SB; off <<= 1) {
        int t = (threadIdx.x >= off) ? s[threadIdx.x - off] : 0;
        __syncthreads();
        s[threadIdx.x] += t;
        __syncthreads();
    }
    if (i < NN) tmp[i] = s[threadIdx.x];
    if (threadIdx.x == SB - 1) bsum[blockIdx.x] = s[SB - 1];
}

__global__ void k_scan2(const int* bsum, int* bcar, int nb) {
    if (threadIdx.x == 0 && blockIdx.x == 0) {
        int c = 0;
        for (int b = 0; b < nb; b++) { bcar[b] = c; c += bsum[b]; }
    }
}

__global__ void k_scan3(const int* tmp, const int* counts, const int* bcar, int* off) {
    int i = blockIdx.x * blockDim.x + threadIdx.x;
    if (i < NN) off[i] = tmp[i] - counts[i] + bcar[i / SB];
}

__global__ void k_scatter(const int* __restrict__ row, const int* __restrict__ col,
                          const int* __restrict__ off, int* __restrict__ cursor,
                          int* __restrict__ sorted) {
    int e = blockIdx.x * blockDim.x + threadIdx.x;
    if (e < NE) {
        int r = row[e];
        int p = off[r] + atomicAdd(&cursor[r], 1);
        sorted[p] = col[e];
    }
}

// ---------------- per-node softmax + aggregation (1 wave / node) ----------------
__global__ __launch_bounds__(256) void k_node(const _Float16* __restrict__ content,
                                              const float* __restrict__ ssrc,
                                              const float* __restrict__ sdst,
                                              const int* __restrict__ counts,
                                              const int* __restrict__ off,
                                              const int* __restrict__ sorted,
                                              const float* __restrict__ bias,
                                              float* __restrict__ out,
                                              float* __restrict__ gpart) {
    __shared__ float gsh[16];
    __shared__ float ash[4][64][4];   // per-wave alpha cache [wave][edge][head]
    __shared__ int   csh[4][64];      // per-wave col cache
    const int w = threadIdx.x >> 6;
    const int lane = threadIdx.x & 63;
    const int n = blockIdx.x * 4 + w;   // NN % 4 == 0
    if (threadIdx.x < 16) gsh[threadIdx.x] = 0.f;
    __syncthreads();

    const int cnt = counts[n], base = off[n];
    const int total = cnt + 1;  // + self loop
    const float4 ss = *(const float4*)&ssrc[n * 4];
    const int hsel = lane >> 4;
    const half4* c4 = (const half4*)content;

    float4 acc = make_float4(0.f, 0.f, 0.f, 0.f);
    float g[10];
#pragma unroll
    for (int k = 0; k < 10; k++) g[k] = 0.f;

    if (total <= 64) {
        // ---- fast path: one edge per lane ----
        const int l = lane;
        const bool act = (l < total);
        const int c = (l < cnt) ? sorted[base + l] : n;
        float4 sd = *(const float4*)&sdst[c * 4];
        float r0 = ss.x + sd.x; r0 = r0 > 0.f ? r0 : NEG * r0;
        float r1 = ss.y + sd.y; r1 = r1 > 0.f ? r1 : NEG * r1;
        float r2 = ss.z + sd.z; r2 = r2 > 0.f ? r2 : NEG * r2;
        float r3 = ss.w + sd.w; r3 = r3 > 0.f ? r3 : NEG * r3;
        float m0 = act ? r0 : -1e30f, m1 = act ? r1 : -1e30f;
        float m2 = act ? r2 : -1e30f, m3 = act ? r3 : -1e30f;
#pragma unroll
        for (int s = 1; s < 64; s <<= 1) {
            m0 = fmaxf(m0, __shfl_xor(m0, s));
            m1 = fmaxf(m1, __shfl_xor(m1, s));
            m2 = fmaxf(m2, __shfl_xor(m2, s));
            m3 = fmaxf(m3, __shfl_xor(m3, s));
        }
        float e0 = act ? __expf(r0 - m0) : 0.f;
        float e1 = act ? __expf(r1 - m1) : 0.f;
        float e2 = act ? __expf(r2 - m2) : 0.f;
        float e3 = act ? __expf(r3 - m3) : 0.f;
        float s0 = e0, s1 = e1, s2 = e2, s3 = e3;
#pragma unroll
        for (int s = 1; s < 64; s <<= 1) {
            s0 += __shfl_xor(s0, s); s1 += __shfl_xor(s1, s);
            s2 += __shfl_xor(s2, s); s3 += __shfl_xor(s3, s);
        }
        float a0 = e0 / (s0 + 1e-16f), a1 = e1 / (s1 + 1e-16f);
        float a2 = e2 / (s2 + 1e-16f), a3 = e3 / (s3 + 1e-16f);

        g[0] = a0 * a0; g[1] = a0 * a1; g[2] = a0 * a2; g[3] = a0 * a3;
        g[4] = a1 * a1; g[5] = a1 * a2; g[6] = a1 * a3;
        g[7] = a2 * a2; g[8] = a2 * a3; g[9] = a3 * a3;

        // inactive lanes: alpha = 0, col = n -> safe padding
        ash[w][l][0] = a0; ash[w][l][1] = a1;
        ash[w][l][2] = a2; ash[w][l][3] = a3;
        csh[w][l] = c;

        // ---- aggregation: branch-free 8-wide, 8 gathers in flight ----
        const int nit = (total + 7) & ~7;
        for (int e = 0; e < nit; e += 8) {
            int   ci[8];
            float bi[8];
#pragma unroll
            for (int u = 0; u < 8; u++) {
                ci[u] = csh[w][e + u];
                bi[u] = ash[w][e + u][hsel];
            }
            half4 vi[8];
#pragma unroll
            for (int u = 0; u < 8; u++) vi[u] = c4[(size_t)ci[u] * 64 + lane];
#pragma unroll
            for (int u = 0; u < 8; u++) {
                acc.x += bi[u] * (float)vi[u][0];
                acc.y += bi[u] * (float)vi[u][1];
                acc.z += bi[u] * (float)vi[u][2];
                acc.w += bi[u] * (float)vi[u][3];
            }
        }
    } else {
        // ---- generic chunked path (degree >= 64; essentially never) ----
        const int nch = (total + 63) >> 6;
        float m0 = -1e30f, m1 = -1e30f, m2 = -1e30f, m3 = -1e30f;
        for (int ch = 0; ch < nch; ch++) {
            int l = ch * 64 + lane;
            if (l < total) {
                int c = (l < cnt) ? sorted[base + l] : n;
                float4 sd = *(const float4*)&sdst[c * 4];
                float r0 = ss.x + sd.x; r0 = r0 > 0.f ? r0 : NEG * r0;
                float r1 = ss.y + sd.y; r1 = r1 > 0.f ? r1 : NEG * r1;
                float r2 = ss.z + sd.z; r2 = r2 > 0.f ? r2 : NEG * r2;
                float r3 = ss.w + sd.w; r3 = r3 > 0.f ? r3 : NEG * r3;
                m0 = fmaxf(m0, r0); m1 = fmaxf(m1, r1);
                m2 = fmaxf(m2, r2); m3 = fmaxf(m3, r3);
            }
        }
#pragma unroll
        for (int s = 1; s < 64; s <<= 1) {
            m0 = fmaxf(m0, __shfl_xor(m0, s));
            m1 = fmaxf(m1, __shfl_xor(m1, s));
            m2 = fmaxf(m2, __shfl_xor(m2, s));
            m3 = fmaxf(m3, __shfl_xor(m3, s));
        }
        float s0 = 0.f, s1 = 0.f, s2 = 0.f, s3 = 0.f;
        for (int ch = 0; ch < nch; ch++) {
            int l = ch * 64 + lane;
            if (l < total) {
                int c = (l < cnt) ? sorted[base + l] : n;
                float4 sd = *(const float4*)&sdst[c * 4];
                float r0 = ss.x + sd.x; r0 = r0 > 0.f ? r0 : NEG * r0;
                float r1 = ss.y + sd.y; r1 = r1 > 0.f ? r1 : NEG * r1;
                float r2 = ss.z + sd.z; r2 = r2 > 0.f ? r2 : NEG * r2;
                float r3 = ss.w + sd.w; r3 = r3 > 0.f ? r3 : NEG * r3;
                s0 += __expf(r0 - m0); s1 += __expf(r1 - m1);
                s2 += __expf(r2 - m2); s3 += __expf(r3 - m3);
            }
        }
#pragma unroll
        for (int s = 1; s < 64; s <<= 1) {
            s0 += __shfl_xor(s0, s); s1 += __shfl_xor(s1, s);
            s2 += __shfl_xor(s2, s); s3 += __shfl_xor(s3, s);
        }
        const float i0 = 1.f / (s0 + 1e-16f), i1 = 1.f / (s1 + 1e-16f);
        const float i2 = 1.f / (s2 + 1e-16f), i3 = 1.f / (s3 + 1e-16f);

        for (int ch = 0; ch < nch; ch++) {
            int l = ch * 64 + lane;
            int c = n;
            float a0 = 0.f, a1 = 0.f, a2 = 0.f, a3 = 0.f;
            if (l < total) {
                c = (l < cnt) ? sorted[base + l] : n;
                float4 sd = *(const float4*)&sdst[c * 4];
                float r0 = ss.x + sd.x; r0 = r0 > 0.f ? r0 : NEG * r0;
                float r1 = ss.y + sd.y; r1 = r1 > 0.f ? r1 : NEG * r1;
                float r2 = ss.z + sd.z; r2 = r2 > 0.f ? r2 : NEG * r2;
                float r3 = ss.w + sd.w; r3 = r3 > 0.f ? r3 : NEG * r3;
                a0 = __expf(r0 - m0) * i0; a1 = __expf(r1 - m1) * i1;
                a2 = __expf(r2 - m2) * i2; a3 = __expf(r3 - m3) * i3;
            }
            g[0] += a0 * a0; g[1] += a0 * a1; g[2] += a0 * a2; g[3] += a0 * a3;
            g[4] += a1 * a1; g[5] += a1 * a2; g[6] += a1 * a3;
            g[7] += a2 * a2; g[8] += a2 * a3; g[9] += a3 * a3;

            int cc = min(64, total - ch * 64);
            for (int e = 0; e < cc; e++) {
                float b0 = __shfl(a0, e), b1 = __shfl(a1, e);
                float b2 = __shfl(a2, e), b3 = __shfl(a3, e);
                int ce = __shfl(c, e);
                float mya = hsel == 0 ? b0 : hsel == 1 ? b1 : hsel == 2 ? b2 : b3;
                half4 cv = c4[(size_t)ce * 64 + lane];
                acc.x += mya * (float)cv[0]; acc.y += mya * (float)cv[1];
                acc.z += mya * (float)cv[2]; acc.w += mya * (float)cv[3];
            }
        }
    }

    float4 bv = ((const float4*)bias)[lane];
    acc.x += bv.x; acc.y += bv.y; acc.z += bv.z; acc.w += bv.w;
    ((float4*)out)[(size_t)n * 64 + lane] = acc;

    // gram: wave reduce -> LDS -> per-block partial STORE (no global atomics)
#pragma unroll
    for (int s = 1; s < 64; s <<= 1) {
#pragma unroll
        for (int k = 0; k < 10; k++) g[k] += __shfl_xor(g[k], s);
    }
    if (lane == 0) {
#pragma unroll
        for (int k = 0; k < 10; k++) atomicAdd(&gsh[k], g[k]);
    }
    __syncthreads();
    if (threadIdx.x < 10) gpart[(size_t)blockIdx.x * 10 + threadIdx.x] = gsh[threadIdx.x];
}

// ---------------- gram reduction + diversity loss ----------------
__global__ __launch_bounds__(1024) void k_final(const float* __restrict__ gpart,
                                                float* __restrict__ out_div) {
    __shared__ float s[1024];
    const int t = threadIdx.x;
    const int k = t & 15, grp = t >> 4;   // 64 groups x 16 slots
    float v = 0.f;
    if (k < 10) {
        for (int b = grp; b < NBLK; b += 64) v += gpart[(size_t)b * 10 + k];
    }
    s[t] = v;
    __syncthreads();
    for (int off = 512; off >= 16; off >>= 1) {
        if (t < off) s[t] += s[t + off];
        __syncthreads();
    }
    if (t == 0) {
        float g00 = s[0], g01 = s[1], g02 = s[2], g03 = s[3];
        float g11 = s[4], g12 = s[5], g13 = s[6];
        float g22 = s[7], g23 = s[8], g33 = s[9];
        float n0 = fmaxf(sqrtf(g00), 1e-8f), n1 = fmaxf(sqrtf(g11), 1e-8f);
        float n2 = fmaxf(sqrtf(g22), 1e-8f), n3 = fmaxf(sqrtf(g33), 1e-8f);
        float sum = g01 / (n0 * n1) + g02 / (n0 * n2) + g03 / (n0 * n3) +
                    g12 / (n1 * n2) + g13 / (n1 * n3) + g23 / (n2 * n3);
        sum *= 2.0f;
        out_div[0] = sum / 16.0f * 0.1f;
    }
}

extern "C" void kernel_launch(void* const* d_in, const int* in_sizes, int n_in,
                              void* d_out, int out_size, void* d_ws, size_t ws_size,
                              hipStream_t stream) {
    const float* x    = (const float*)d_in[0];
    const int*   ei   = (const int*)d_in[1];
    const int*   row  = ei;
    const int*   col  = ei + NE;
    const float* w    = (const float*)d_in[2];
    const float* att  = (const float*)d_in[3];
    const float* patt = (const float*)d_in[4];
    const float* bias = (const float*)d_in[5];
    float* out = (float*)d_out;

    char* p = (char*)d_ws;
    _Float16* content = (_Float16*)p; p += (size_t)NN * 256 * 2;
    float* ssrc    = (float*)p; p += (size_t)NN * 4 * 4;
    float* sdst    = (float*)p; p += (size_t)NN * 4 * 4;
    float* gpart   = (float*)p; p += (size_t)NBLK * 10 * 4;
    int* counts    = (int*)p;   p += (size_t)NN * 4;
    int* cursor    = (int*)p;   p += (size_t)NN * 4;
    int* offs      = (int*)p;   p += (size_t)NN * 4;
    int* tmp       = (int*)p;   p += (size_t)NN * 4;
    int* bsum      = (int*)p;   p += 64 * 4;
    int* bcar      = (int*)p;   p += 64 * 4;
    int* sorted    = (int*)p;   p += (size_t)NE * 4;

    k_zero<<<(NN + 255) / 256, 256, 0, stream>>>(counts, cursor);

    k_gemm<<<(NN + 63) / 64, 256, 0, stream>>>(x, w, content);
    k_score<<<NN / 4, 256, 0, stream>>>(content, x, att, patt, ssrc, sdst);

    k_count<<<(NE + 255) / 256, 256, 0, stream>>>(row, counts);
    int nb1 = (NN + SB - 1) / SB;
    k_scan1<<<nb1, SB, 0, stream>>>(counts, tmp, bsum);
    k_scan2<<<1, 64, 0, stream>>>(bsum, bcar, nb1);
    k_scan3<<<(NN + 255) / 256, 256, 0, stream>>>(tmp, counts, bcar, offs);
    k_scatter<<<(NE + 255) / 256, 256, 0, stream>>>(row, col, offs, cursor, sorted);

    k_node<<<NBLK, 256, 0, stream>>>(content, ssrc, sdst, counts, offs, sorted,
                                     bias, out, gpart);
    k_final<<<1, 1024, 0, stream>>>(gpart, out + (size_t)NN * 256);
}

// Round 4
// 304.355 us; speedup vs baseline: 1.4821x; 1.1095x over previous
//
#include <hip/hip_runtime.h>
#include <math.h>

#define NN 50000
#define NE 500000
#define HH 4
#define CC 64
#define HC 256
#define PD 16
#define XD 272
#define NEG 0.2f
#define SB 1024
#define NBLK (NN / 4)   // k_node blocks

typedef _Float16 half4 __attribute__((ext_vector_type(4)));
typedef _Float16 half8 __attribute__((ext_vector_type(8)));
typedef float floatx4 __attribute__((ext_vector_type(4)));

#define SA 40   // LDS A-tile row stride in halves (32 + 8 pad)

// ---------------- prep: zero counts + swizzle W into fp16 MFMA-fragment order ----------------
// wfrag[(((kt*4+wv)*4+nt)*64 + lane)*8 + j] = W[wv*64+nt*16+(lane&15)][kt*32+(lane>>4)*8+j]
__global__ void k_prep(const float* __restrict__ w, _Float16* __restrict__ wfrag,
                       int* __restrict__ counts) {
    int idx = blockIdx.x * blockDim.x + threadIdx.x;   // 65536 threads
    if (idx < NN) counts[idx] = 0;
    int j = idx & 7, lane = (idx >> 3) & 63, nt = (idx >> 9) & 3;
    int wv = (idx >> 11) & 3, kt = idx >> 13;
    int n = wv * 64 + nt * 16 + (lane & 15);
    int k = kt * 32 + (lane >> 4) * 8 + j;
    wfrag[idx] = (_Float16)w[(size_t)n * 256 + k];
}

// ---------------- MFMA GEMM: content(fp16) = Xc @ W^T, fused attention scores ----------------
// block = 256 thr (4 waves). Tile: 64 nodes x 256 cols. wave wv owns cols [wv*64,wv*64+64) = head wv.
// B fragments load straight from wfrag (global, L2-hot); only A stages through LDS.
__global__ __launch_bounds__(256) void k_gemm(const float* __restrict__ x,
                                              const _Float16* __restrict__ wfrag,
                                              const float* __restrict__ att,
                                              const float* __restrict__ patt,
                                              _Float16* __restrict__ content,
                                              float* __restrict__ ssrc,
                                              float* __restrict__ sdst) {
    __shared__ _Float16 As[64 * SA];    // [m][k]
    const int tid = threadIdx.x;
    const int wv = tid >> 6, lane = tid & 63;
    const int nb = blockIdx.x * 64;
    const int m16 = lane & 15, q = lane >> 4;

    floatx4 acc[4][4];
#pragma unroll
    for (int mt = 0; mt < 4; mt++)
#pragma unroll
        for (int nt = 0; nt < 4; nt++) acc[mt][nt] = (floatx4){0.f, 0.f, 0.f, 0.f};

    const int arow = tid >> 2, akq = (tid & 3) * 8;
    const int anode = nb + arow;

#pragma unroll
    for (int kt = 0; kt < 8; kt++) {
        const int k0 = kt * 32;
        __syncthreads();
        // stage A: 64 rows x 32 k (fp32 -> fp16)
        float4 f0 = make_float4(0.f, 0.f, 0.f, 0.f), f1 = f0;
        if (anode < NN) {
            f0 = *(const float4*)&x[(size_t)anode * XD + k0 + akq];
            f1 = *(const float4*)&x[(size_t)anode * XD + k0 + akq + 4];
        }
        half8 hv;
        hv[0] = (_Float16)f0.x; hv[1] = (_Float16)f0.y;
        hv[2] = (_Float16)f0.z; hv[3] = (_Float16)f0.w;
        hv[4] = (_Float16)f1.x; hv[5] = (_Float16)f1.y;
        hv[6] = (_Float16)f1.z; hv[7] = (_Float16)f1.w;
        *(half8*)&As[arow * SA + akq] = hv;
        __syncthreads();

        half8 af[4], bf[4];
#pragma unroll
        for (int nt = 0; nt < 4; nt++)
            bf[nt] = *(const half8*)&wfrag[((((size_t)kt * 4 + wv) * 4 + nt) * 64 + lane) * 8];
#pragma unroll
        for (int mt = 0; mt < 4; mt++)
            af[mt] = *(half8*)&As[(mt * 16 + m16) * SA + q * 8];
#pragma unroll
        for (int mt = 0; mt < 4; mt++)
#pragma unroll
            for (int nt = 0; nt < 4; nt++)
                acc[mt][nt] = __builtin_amdgcn_mfma_f32_16x16x32_f16(
                    af[mt], bf[nt], acc[mt][nt], 0, 0, 0);
    }

    // epilogue: D layout col(in head) = nt*16 + (lane&15), node = nb + mt*16 + q*4 + r
    // head h = wv. Fused scores: sa = content . att[h][:64] (+pos), sb = . att[h][64:]
    const int h = wv;
#pragma unroll
    for (int mt = 0; mt < 4; mt++) {
#pragma unroll
        for (int r = 0; r < 4; r++) {
            int node = nb + mt * 16 + q * 4 + r;
            if (node < NN) {
                float sa = 0.f, sb = 0.f;
#pragma unroll
                for (int nt = 0; nt < 4; nt++) {
                    float v = acc[mt][nt][r];
                    int cih = nt * 16 + m16;
                    content[(size_t)node * 256 + h * 64 + cih] = (_Float16)v;
                    sa += v * att[h * 128 + cih];
                    sb += v * att[h * 128 + 64 + cih];
                }
                // pos contribution: lane m16 takes pos dim m16
                float pv = x[(size_t)node * XD + 256 + m16];
                sa += pv * patt[h * 32 + m16];
                sb += pv * patt[h * 32 + 16 + m16];
#pragma unroll
                for (int m = 1; m < 16; m <<= 1) {
                    sa += __shfl_xor(sa, m, 64);
                    sb += __shfl_xor(sb, m, 64);
                }
                if (m16 == 0) {
                    ssrc[node * 4 + h] = sa;
                    sdst[node * 4 + h] = sb;
                }
            }
        }
    }
}

// ---------------- edge bucketing by row (count returns slot; place is atomic-free) ----------------
__global__ void k_count(const int* __restrict__ row, int* __restrict__ counts,
                        int* __restrict__ slot) {
    int e = blockIdx.x * blockDim.x + threadIdx.x;
    if (e < NE) slot[e] = atomicAdd(&counts[row[e]], 1);
}

__global__ __launch_bounds__(SB) void k_scan1(const int* __restrict__ counts, int* tmp, int* bsum) {
    __shared__ int s[SB];
    int i = blockIdx.x * SB + threadIdx.x;
    int v = (i < NN) ? counts[i] : 0;
    s[threadIdx.x] = v;
    __syncthreads();
    for (int off = 1; off < SB; off <<= 1) {
        int t = (threadIdx.x >= off) ? s[threadIdx.x - off] : 0;
        __syncthreads();
        s[threadIdx.x] += t;
        __syncthreads();
    }
    if (i < NN) tmp[i] = s[threadIdx.x];
    if (threadIdx.x == SB - 1) bsum[blockIdx.x] = s[SB - 1];
}

__global__ void k_scan2(const int* __restrict__ bsum, int* __restrict__ bcar, int nb) {
    int lane = threadIdx.x;           // one wave
    int v = (lane < nb) ? bsum[lane] : 0;
#pragma unroll
    for (int off = 1; off < 64; off <<= 1) {
        int t = __shfl_up(v, off);
        if (lane >= off) v += t;
    }
    if (lane < nb) bcar[lane] = v - bsum[lane];   // exclusive
}

__global__ void k_scan3(const int* tmp, const int* counts, const int* bcar, int* off) {
    int i = blockIdx.x * blockDim.x + threadIdx.x;
    if (i < NN) off[i] = tmp[i] - counts[i] + bcar[i / SB];
}

__global__ void k_place(const int* __restrict__ row, const int* __restrict__ col,
                        const int* __restrict__ offs, const int* __restrict__ slot,
                        int* __restrict__ sorted) {
    int e = blockIdx.x * blockDim.x + threadIdx.x;
    if (e < NE) sorted[offs[row[e]] + slot[e]] = col[e];
}

// ---------------- per-node softmax + aggregation (1 wave / node) ----------------
__global__ __launch_bounds__(256) void k_node(const _Float16* __restrict__ content,
                                              const float* __restrict__ ssrc,
                                              const float* __restrict__ sdst,
                                              const int* __restrict__ counts,
                                              const int* __restrict__ off,
                                              const int* __restrict__ sorted,
                                              const float* __restrict__ bias,
                                              float* __restrict__ out,
                                              float* __restrict__ gpart) {
    __shared__ float gsh[16];
    __shared__ float ash[4][64][4];   // per-wave alpha cache [wave][edge][head]
    __shared__ int   csh[4][64];      // per-wave col cache
    const int w = threadIdx.x >> 6;
    const int lane = threadIdx.x & 63;
    const int n = blockIdx.x * 4 + w;   // NN % 4 == 0
    if (threadIdx.x < 16) gsh[threadIdx.x] = 0.f;
    __syncthreads();

    const int cnt = counts[n], base = off[n];
    const int total = cnt + 1;  // + self loop
    const float4 ss = *(const float4*)&ssrc[n * 4];
    const int hsel = lane >> 4;
    const half4* c4 = (const half4*)content;

    float4 acc = make_float4(0.f, 0.f, 0.f, 0.f);
    float g[10];
#pragma unroll
    for (int k = 0; k < 10; k++) g[k] = 0.f;

    if (total <= 64) {
        // ---- fast path: one edge per lane ----
        const int l = lane;
        const bool act = (l < total);
        const int c = (l < cnt) ? sorted[base + l] : n;
        float4 sd = *(const float4*)&sdst[c * 4];
        float r0 = ss.x + sd.x; r0 = r0 > 0.f ? r0 : NEG * r0;
        float r1 = ss.y + sd.y; r1 = r1 > 0.f ? r1 : NEG * r1;
        float r2 = ss.z + sd.z; r2 = r2 > 0.f ? r2 : NEG * r2;
        float r3 = ss.w + sd.w; r3 = r3 > 0.f ? r3 : NEG * r3;
        float m0 = act ? r0 : -1e30f, m1 = act ? r1 : -1e30f;
        float m2 = act ? r2 : -1e30f, m3 = act ? r3 : -1e30f;
#pragma unroll
        for (int s = 1; s < 64; s <<= 1) {
            m0 = fmaxf(m0, __shfl_xor(m0, s));
            m1 = fmaxf(m1, __shfl_xor(m1, s));
            m2 = fmaxf(m2, __shfl_xor(m2, s));
            m3 = fmaxf(m3, __shfl_xor(m3, s));
        }
        float e0 = act ? __expf(r0 - m0) : 0.f;
        float e1 = act ? __expf(r1 - m1) : 0.f;
        float e2 = act ? __expf(r2 - m2) : 0.f;
        float e3 = act ? __expf(r3 - m3) : 0.f;
        float s0 = e0, s1 = e1, s2 = e2, s3 = e3;
#pragma unroll
        for (int s = 1; s < 64; s <<= 1) {
            s0 += __shfl_xor(s0, s); s1 += __shfl_xor(s1, s);
            s2 += __shfl_xor(s2, s); s3 += __shfl_xor(s3, s);
        }
        float a0 = e0 / (s0 + 1e-16f), a1 = e1 / (s1 + 1e-16f);
        float a2 = e2 / (s2 + 1e-16f), a3 = e3 / (s3 + 1e-16f);

        g[0] = a0 * a0; g[1] = a0 * a1; g[2] = a0 * a2; g[3] = a0 * a3;
        g[4] = a1 * a1; g[5] = a1 * a2; g[6] = a1 * a3;
        g[7] = a2 * a2; g[8] = a2 * a3; g[9] = a3 * a3;

        // inactive lanes: alpha = 0, col = n -> safe padding
        ash[w][l][0] = a0; ash[w][l][1] = a1;
        ash[w][l][2] = a2; ash[w][l][3] = a3;
        csh[w][l] = c;

        // ---- aggregation: branch-free 16-wide, 16 gathers in flight ----
        const int nit = (total + 15) & ~15;
        for (int e = 0; e < nit; e += 16) {
            int   ci[16];
            float bi[16];
#pragma unroll
            for (int u = 0; u < 16; u++) {
                ci[u] = csh[w][e + u];
                bi[u] = ash[w][e + u][hsel];
            }
            half4 vi[16];
#pragma unroll
            for (int u = 0; u < 16; u++) vi[u] = c4[(size_t)ci[u] * 64 + lane];
#pragma unroll
            for (int u = 0; u < 16; u++) {
                acc.x += bi[u] * (float)vi[u][0];
                acc.y += bi[u] * (float)vi[u][1];
                acc.z += bi[u] * (float)vi[u][2];
                acc.w += bi[u] * (float)vi[u][3];
            }
        }
    } else {
        // ---- generic chunked path (degree >= 64; essentially never) ----
        const int nch = (total + 63) >> 6;
        float m0 = -1e30f, m1 = -1e30f, m2 = -1e30f, m3 = -1e30f;
        for (int ch = 0; ch < nch; ch++) {
            int l = ch * 64 + lane;
            if (l < total) {
                int c = (l < cnt) ? sorted[base + l] : n;
                float4 sd = *(const float4*)&sdst[c * 4];
                float r0 = ss.x + sd.x; r0 = r0 > 0.f ? r0 : NEG * r0;
                float r1 = ss.y + sd.y; r1 = r1 > 0.f ? r1 : NEG * r1;
                float r2 = ss.z + sd.z; r2 = r2 > 0.f ? r2 : NEG * r2;
                float r3 = ss.w + sd.w; r3 = r3 > 0.f ? r3 : NEG * r3;
                m0 = fmaxf(m0, r0); m1 = fmaxf(m1, r1);
                m2 = fmaxf(m2, r2); m3 = fmaxf(m3, r3);
            }
        }
#pragma unroll
        for (int s = 1; s < 64; s <<= 1) {
            m0 = fmaxf(m0, __shfl_xor(m0, s));
            m1 = fmaxf(m1, __shfl_xor(m1, s));
            m2 = fmaxf(m2, __shfl_xor(m2, s));
            m3 = fmaxf(m3, __shfl_xor(m3, s));
        }
        float s0 = 0.f, s1 = 0.f, s2 = 0.f, s3 = 0.f;
        for (int ch = 0; ch < nch; ch++) {
            int l = ch * 64 + lane;
            if (l < total) {
                int c = (l < cnt) ? sorted[base + l] : n;
                float4 sd = *(const float4*)&sdst[c * 4];
                float r0 = ss.x + sd.x; r0 = r0 > 0.f ? r0 : NEG * r0;
                float r1 = ss.y + sd.y; r1 = r1 > 0.f ? r1 : NEG * r1;
                float r2 = ss.z + sd.z; r2 = r2 > 0.f ? r2 : NEG * r2;
                float r3 = ss.w + sd.w; r3 = r3 > 0.f ? r3 : NEG * r3;
                s0 += __expf(r0 - m0); s1 += __expf(r1 - m1);
                s2 += __expf(r2 - m2); s3 += __expf(r3 - m3);
            }
        }
#pragma unroll
        for (int s = 1; s < 64; s <<= 1) {
            s0 += __shfl_xor(s0, s); s1 += __shfl_xor(s1, s);
            s2 += __shfl_xor(s2, s); s3 += __shfl_xor(s3, s);
        }
        const float i0 = 1.f / (s0 + 1e-16f), i1 = 1.f / (s1 + 1e-16f);
        const float i2 = 1.f / (s2 + 1e-16f), i3 = 1.f / (s3 + 1e-16f);

        for (int ch = 0; ch < nch; ch++) {
            int l = ch * 64 + lane;
            int c = n;
            float a0 = 0.f, a1 = 0.f, a2 = 0.f, a3 = 0.f;
            if (l < total) {
                c = (l < cnt) ? sorted[base + l] : n;
                float4 sd = *(const float4*)&sdst[c * 4];
                float r0 = ss.x + sd.x; r0 = r0 > 0.f ? r0 : NEG * r0;
                float r1 = ss.y + sd.y; r1 = r1 > 0.f ? r1 : NEG * r1;
                float r2 = ss.z + sd.z; r2 = r2 > 0.f ? r2 : NEG * r2;
                float r3 = ss.w + sd.w; r3 = r3 > 0.f ? r3 : NEG * r3;
                a0 = __expf(r0 - m0) * i0; a1 = __expf(r1 - m1) * i1;
                a2 = __expf(r2 - m2) * i2; a3 = __expf(r3 - m3) * i3;
            }
            g[0] += a0 * a0; g[1] += a0 * a1; g[2] += a0 * a2; g[3] += a0 * a3;
            g[4] += a1 * a1; g[5] += a1 * a2; g[6] += a1 * a3;
            g[7] += a2 * a2; g[8] += a2 * a3; g[9] += a3 * a3;

            int cc = min(64, total - ch * 64);
            for (int e = 0; e < cc; e++) {
                float b0 = __shfl(a0, e), b1 = __shfl(a1, e);
                float b2 = __shfl(a2, e), b3 = __shfl(a3, e);
                int ce = __shfl(c, e);
                float mya = hsel == 0 ? b0 : hsel == 1 ? b1 : hsel == 2 ? b2 : b3;
                half4 cv = c4[(size_t)ce * 64 + lane];
                acc.x += mya * (float)cv[0]; acc.y += mya * (float)cv[1];
                acc.z += mya * (float)cv[2]; acc.w += mya * (float)cv[3];
            }
        }
    }

    float4 bv = ((const float4*)bias)[lane];
    acc.x += bv.x; acc.y += bv.y; acc.z += bv.z; acc.w += bv.w;
    ((float4*)out)[(size_t)n * 64 + lane] = acc;

    // gram: wave reduce -> LDS -> per-block partial STORE (no global atomics)
#pragma unroll
    for (int s = 1; s < 64; s <<= 1) {
#pragma unroll
        for (int k = 0; k < 10; k++) g[k] += __shfl_xor(g[k], s);
    }
    if (lane == 0) {
#pragma unroll
        for (int k = 0; k < 10; k++) atomicAdd(&gsh[k], g[k]);
    }
    __syncthreads();
    if (threadIdx.x < 10) gpart[(size_t)blockIdx.x * 10 + threadIdx.x] = gsh[threadIdx.x];
}

// ---------------- gram reduction + diversity loss ----------------
__global__ __launch_bounds__(1024) void k_final(const float* __restrict__ gpart,
                                                float* __restrict__ out_div) {
    __shared__ float s[1024];
    const int t = threadIdx.x;
    const int k = t & 15, grp = t >> 4;   // 64 groups x 16 slots
    float v = 0.f;
    if (k < 10) {
        for (int b = grp; b < NBLK; b += 64) v += gpart[(size_t)b * 10 + k];
    }
    s[t] = v;
    __syncthreads();
    for (int off = 512; off >= 16; off >>= 1) {
        if (t < off) s[t] += s[t + off];
        __syncthreads();
    }
    if (t == 0) {
        float g00 = s[0], g01 = s[1], g02 = s[2], g03 = s[3];
        float g11 = s[4], g12 = s[5], g13 = s[6];
        float g22 = s[7], g23 = s[8], g33 = s[9];
        float n0 = fmaxf(sqrtf(g00), 1e-8f), n1 = fmaxf(sqrtf(g11), 1e-8f);
        float n2 = fmaxf(sqrtf(g22), 1e-8f), n3 = fmaxf(sqrtf(g33), 1e-8f);
        float sum = g01 / (n0 * n1) + g02 / (n0 * n2) + g03 / (n0 * n3) +
                    g12 / (n1 * n2) + g13 / (n1 * n3) + g23 / (n2 * n3);
        sum *= 2.0f;
        out_div[0] = sum / 16.0f * 0.1f;
    }
}

extern "C" void kernel_launch(void* const* d_in, const int* in_sizes, int n_in,
                              void* d_out, int out_size, void* d_ws, size_t ws_size,
                              hipStream_t stream) {
    const float* x    = (const float*)d_in[0];
    const int*   ei   = (const int*)d_in[1];
    const int*   row  = ei;
    const int*   col  = ei + NE;
    const float* w    = (const float*)d_in[2];
    const float* att  = (const float*)d_in[3];
    const float* patt = (const float*)d_in[4];
    const float* bias = (const float*)d_in[5];
    float* out = (float*)d_out;

    char* p = (char*)d_ws;
    _Float16* content = (_Float16*)p; p += (size_t)NN * 256 * 2;
    _Float16* wfrag   = (_Float16*)p; p += (size_t)256 * 256 * 2;
    float* ssrc    = (float*)p; p += (size_t)NN * 4 * 4;
    float* sdst    = (float*)p; p += (size_t)NN * 4 * 4;
    float* gpart   = (float*)p; p += (size_t)NBLK * 10 * 4;
    int* counts    = (int*)p;   p += (size_t)NN * 4;
    int* offs      = (int*)p;   p += (size_t)NN * 4;
    int* tmp       = (int*)p;   p += (size_t)NN * 4;
    int* bsum      = (int*)p;   p += 64 * 4;
    int* bcar      = (int*)p;   p += 64 * 4;
    int* slot      = (int*)p;   p += (size_t)NE * 4;
    int* sorted    = (int*)p;   p += (size_t)NE * 4;

    k_prep<<<256, 256, 0, stream>>>(w, wfrag, counts);

    k_count<<<(NE + 255) / 256, 256, 0, stream>>>(row, counts, slot);

    k_gemm<<<(NN + 63) / 64, 256, 0, stream>>>(x, wfrag, att, patt, content, ssrc, sdst);

    int nb1 = (NN + SB - 1) / SB;
    k_scan1<<<nb1, SB, 0, stream>>>(counts, tmp, bsum);
    k_scan2<<<1, 64, 0, stream>>>(bsum, bcar, nb1);
    k_scan3<<<(NN + 255) / 256, 256, 0, stream>>>(tmp, counts, bcar, offs);
    k_place<<<(NE + 255) / 256, 256, 0, stream>>>(row, col, offs, slot, sorted);

    k_node<<<NBLK, 256, 0, stream>>>(content, ssrc, sdst, counts, offs, sorted,
                                     bias, out, gpart);
    k_final<<<1, 1024, 0, stream>>>(gpart, out + (size_t)NN * 256);
}